// Round 7
// baseline (348.447 us; speedup 1.0000x reference)
//
#include <hip/hip_runtime.h>

// L2Q attention, fp16-MFMA, hi/lo split on q/k path AND proj GEMM.
// B=8, N=1024, C=768, H=12, d=64, 3C=2304, M=B*N=8192.
// R7: attn reads V^T fragments direct from global (K stays in LDS hi/lo;
//     LDS 48->32KB, occupancy up, barrier drain down) — bit-identical math;
//     proj retiled 128x64 (768 blocks, was 384 at 1.5/CU) — bit-identical.

typedef _Float16 f16x8 __attribute__((ext_vector_type(8)));
typedef _Float16 f16x4 __attribute__((ext_vector_type(4)));
typedef float f32x4 __attribute__((ext_vector_type(4)));

#define NB 8
#define NN 1024
#define NC 768
#define NH 12
#define ND 64
#define TC 2304
#define NM 8192

__device__ __forceinline__ void async16(const void* g, void* l) {
    __builtin_amdgcn_global_load_lds(
        (const __attribute__((address_space(1))) void*)g,
        (__attribute__((address_space(3))) void*)l, 16, 0, 0);
}

// ---------------- fp32 -> fp16 hi/lo split ----------------
__global__ void cvt_split_f32(const float* __restrict__ s, _Float16* __restrict__ hi,
                              _Float16* __restrict__ lo, int n4) {
    int i = blockIdx.x * 256 + threadIdx.x;
    if (i < n4) {
        float4 v = ((const float4*)s)[i];
        f16x4 h, l;
        h[0] = (_Float16)v.x; l[0] = (_Float16)(v.x - (float)h[0]);
        h[1] = (_Float16)v.y; l[1] = (_Float16)(v.y - (float)h[1]);
        h[2] = (_Float16)v.z; l[2] = (_Float16)(v.z - (float)h[2]);
        h[3] = (_Float16)v.w; l[3] = (_Float16)(v.w - (float)h[3]);
        ((f16x4*)hi)[i] = h;
        ((f16x4*)lo)[i] = l;
    }
}

// ---------------- qkv GEMM: C[8192,2304] = X * Wqkv^T ----------------
// q/k columns: 3-term split, term-major (hh x16, lh x16, hl x16). v: 1-term.
__global__ __launch_bounds__(256) void gemm_qkv(
    const _Float16* __restrict__ Ah, const _Float16* __restrict__ Al,
    const _Float16* __restrict__ Bh, const _Float16* __restrict__ Bl,
    _Float16* __restrict__ qh, _Float16* __restrict__ ql,
    _Float16* __restrict__ kh, _Float16* __restrict__ kl,
    _Float16* __restrict__ vt16)
{
    __shared__ __align__(16) _Float16 sAh[128 * 32];
    __shared__ __align__(16) _Float16 sAl[128 * 32];
    __shared__ __align__(16) _Float16 sBh[128 * 32];
    __shared__ __align__(16) _Float16 sBl[128 * 32];
    const int tid = threadIdx.x;
    const int lane = tid & 63, wv = tid >> 6;
    const int quad = lane >> 4, l16 = lane & 15;
    const int wm = (wv >> 1) * 64, wn = (wv & 1) * 64;
    const int m0 = blockIdx.x * 128, n0 = blockIdx.y * 128;
    const bool is_v = (n0 >= 2 * NC);

    f32x4 acc[4][4] = {};

    for (int k0 = 0; k0 < NC; k0 += 32) {
#pragma unroll
        for (int i = 0; i < 2; i++) {
            int c = tid + i * 256;
            int r = c >> 2, kc = c & 3;
            size_t goA = (size_t)(m0 + r) * NC + k0 + kc * 8;
            size_t goB = (size_t)(n0 + r) * NC + k0 + kc * 8;
            async16(Ah + goA, sAh + c * 8);
            async16(Bh + goB, sBh + c * 8);
            if (!is_v) {
                async16(Al + goA, sAl + c * 8);
                async16(Bl + goB, sBl + c * 8);
            }
        }
        __syncthreads();
        f16x8 ah[4], bh[4];
#pragma unroll
        for (int t = 0; t < 4; t++) {
            ah[t] = *(const f16x8*)(sAh + (wm + t * 16 + l16) * 32 + quad * 8);
            bh[t] = *(const f16x8*)(sBh + (wn + t * 16 + l16) * 32 + quad * 8);
        }
        // term 1: hh (16 independent MFMAs)
#pragma unroll
        for (int i = 0; i < 4; i++)
#pragma unroll
            for (int j = 0; j < 4; j++)
                acc[i][j] = __builtin_amdgcn_mfma_f32_16x16x32_f16(ah[i], bh[j], acc[i][j], 0, 0, 0);
        if (!is_v) {
            f16x8 al[4], bl[4];
#pragma unroll
            for (int t = 0; t < 4; t++) {
                al[t] = *(const f16x8*)(sAl + (wm + t * 16 + l16) * 32 + quad * 8);
                bl[t] = *(const f16x8*)(sBl + (wn + t * 16 + l16) * 32 + quad * 8);
            }
            // term 2: lh
#pragma unroll
            for (int i = 0; i < 4; i++)
#pragma unroll
                for (int j = 0; j < 4; j++)
                    acc[i][j] = __builtin_amdgcn_mfma_f32_16x16x32_f16(al[i], bh[j], acc[i][j], 0, 0, 0);
            // term 3: hl
#pragma unroll
            for (int i = 0; i < 4; i++)
#pragma unroll
                for (int j = 0; j < 4; j++)
                    acc[i][j] = __builtin_amdgcn_mfma_f32_16x16x32_f16(ah[i], bl[j], acc[i][j], 0, 0, 0);
        }
        __syncthreads();
    }

    // epilogue: q,k as hi/lo pairs [B,H,N,d]; v^T fp16 [B,H,d,N]
#pragma unroll
    for (int i = 0; i < 4; i++) {
#pragma unroll
        for (int j = 0; j < 4; j++) {
#pragma unroll
            for (int r = 0; r < 4; r++) {
                int row = m0 + wm + i * 16 + quad * 4 + r;
                int col = n0 + wn + j * 16 + l16;
                float fv = acc[i][j][r];
                int b = row >> 10, nr = row & 1023;
                int which = col / NC;
                int w2 = col - which * NC;
                int h = w2 >> 6, dd = w2 & 63;
                int bhd = b * NH + h;
                size_t idx = ((size_t)(bhd * NN + nr)) * ND + dd;
                if (which == 0) {
                    _Float16 hv = (_Float16)fv;
                    qh[idx] = hv;
                    ql[idx] = (_Float16)(fv - (float)hv);
                } else if (which == 1) {
                    _Float16 hv = (_Float16)fv;
                    kh[idx] = hv;
                    kl[idx] = (_Float16)(fv - (float)hv);
                } else {
                    vt16[((size_t)(bhd * ND + dd)) * NN + nr] = (_Float16)fv;
                }
            }
        }
    }
}

// ---------------- fused quadratic-ReLU attention ----------------
// grid (8 q-tiles, 96 bh), 256 threads = 4 waves; wave handles 32 q-rows.
// S^T = K*Q^T; K-row assignment per fragment (ks2,T): lane i covers kv row
// ks2*32 + 8*(i>>2) + 4T + (i&3), so S^T acc (quad,l16,reg r) IS element
// (4T|r) of the PV B-fragment on the same lane (register re-pack).
// K in LDS (fragment-major, conflict-free); V^T fragments DIRECT from global
// (L1/L2-served, 8x reuse across qt blocks) — no sVt, smaller barrier drain.
__global__ __launch_bounds__(256) void attn_kernel(
    const _Float16* __restrict__ qhp, const _Float16* __restrict__ qlp,
    const _Float16* __restrict__ khp, const _Float16* __restrict__ klp,
    const _Float16* __restrict__ vt16, float* __restrict__ outh32,
    const float* __restrict__ alpha, const float* __restrict__ beta,
    const float* __restrict__ gamma)
{
    const int qt = blockIdx.x, bh = blockIdx.y;
    const int b = bh / NH, h = bh - b * NH;
    const int tid = threadIdx.x, lane = tid & 63, wv = tid >> 6;
    const int quad = lane >> 4, l16 = lane & 15;
    const float a2 = alpha[h] * 0.015625f;   // alpha * SCALE^2
    const float b1 = beta[h] * 0.125f;       // beta * SCALE
    const float g0 = gamma[h];

    __shared__ __align__(16) _Float16 sKh[128 * 64];  // 16 KB, fragment-major
    __shared__ __align__(16) _Float16 sKl[128 * 64];  // 16 KB, fragment-major

    const size_t qoff = ((size_t)(bh * NN + qt * 128)) * ND;
    const _Float16* Qh = qhp + qoff;
    const _Float16* Ql = qlp + qoff;
    const _Float16* Kh = khp + (size_t)bh * NN * ND;
    const _Float16* Kl = klp + (size_t)bh * NN * ND;
    const _Float16* Vb = vt16 + (size_t)bh * ND * NN;

    // Q fragments (hi and lo): 2 m-tiles x 2 d-chunks (MFMA B-operand)
    f16x8 qfh[2][2], qfl[2][2];
#pragma unroll
    for (int mt = 0; mt < 2; mt++)
#pragma unroll
        for (int ksd = 0; ksd < 2; ksd++) {
            size_t o = (size_t)(wv * 32 + mt * 16 + l16) * ND + ksd * 32 + quad * 8;
            qfh[mt][ksd] = *(const f16x8*)(Qh + o);
            qfl[mt][ksd] = *(const f16x8*)(Ql + o);
        }

    f32x4 O[4][2] = {};        // [dt][mt]
    float dsum[2] = {0.f, 0.f};

    for (int kt = 0; kt < 8; kt++) {
        // ---- stage K hi/lo, fragment-major: frag f=(ks2,T,ksd), chunk
        // P = f*64 + q*16 + (a*4+b) holds K[row=ks2*32+8a+4T+b][k=(ksd*4+q)*8..]
#pragma unroll
        for (int i = 0; i < 4; i++) {
            int P = tid + i * 256;
            int f = P >> 6, q = (P >> 4) & 3, a = (P >> 2) & 3, bb = P & 3;
            int ks2 = f >> 2, T = (f >> 1) & 1, ksd = f & 1;
            int row = ks2 * 32 + 8 * a + 4 * T + bb;
            size_t src = (size_t)(kt * 128 + row) * ND + (ksd * 4 + q) * 8;
            async16(Kh + src, sKh + P * 8);
            async16(Kl + src, sKl + P * 8);
        }
        __syncthreads();

        // ---- QK^T: 8 concurrent S chains (mt x ks2), T-major phases ----
        f16x8 bfrag[2][4];
#pragma unroll
        for (int T = 0; T < 2; T++) {
            f32x4 S[2][4] = {};
#pragma unroll
            for (int ks2 = 0; ks2 < 4; ks2++) {
#pragma unroll
                for (int ksd = 0; ksd < 2; ksd++) {
                    int addr = (((ks2 * 4 + T * 2 + ksd) * 64) + quad * 16 + l16) * 8;
                    f16x8 ah = *(const f16x8*)(sKh + addr);
                    f16x8 al = *(const f16x8*)(sKl + addr);
#pragma unroll
                    for (int mt = 0; mt < 2; mt++) {
                        S[mt][ks2] = __builtin_amdgcn_mfma_f32_16x16x32_f16(ah, qfh[mt][ksd], S[mt][ks2], 0, 0, 0);
                        S[mt][ks2] = __builtin_amdgcn_mfma_f32_16x16x32_f16(al, qfh[mt][ksd], S[mt][ks2], 0, 0, 0);
                        S[mt][ks2] = __builtin_amdgcn_mfma_f32_16x16x32_f16(ah, qfl[mt][ks2 & 1 ? ksd : ksd], S[mt][ks2], 0, 0, 0);
                    }
                }
            }
            // poly + fp16 round; consistent denominator; pack PV B-fragments
#pragma unroll
            for (int mt = 0; mt < 2; mt++) {
#pragma unroll
                for (int ks2 = 0; ks2 < 4; ks2++) {
#pragma unroll
                    for (int r = 0; r < 4; r++) {
                        float s = S[mt][ks2][r];
                        float w = fmaxf(fmaf(fmaf(a2, s, b1), s, g0), 0.f);
                        _Float16 wh = (_Float16)w;
                        dsum[mt] += (float)wh;
                        bfrag[mt][ks2][(T << 2) | r] = wh;
                    }
                }
            }
        }

        // ---- O += V^T x P^T (A = V^T frags from GLOBAL, B = bfrag regs) ----
#pragma unroll
        for (int ks2 = 0; ks2 < 4; ks2++) {
#pragma unroll
            for (int dt = 0; dt < 4; dt++) {
                f16x8 vf = *(const f16x8*)(Vb + (size_t)(dt * 16 + l16) * NN
                                           + kt * 128 + (ks2 * 4 + quad) * 8);
#pragma unroll
                for (int mt = 0; mt < 2; mt++)
                    O[dt][mt] = __builtin_amdgcn_mfma_f32_16x16x32_f16(vf, bfrag[mt][ks2], O[dt][mt], 0, 0, 0);
            }
        }
        __syncthreads();   // compute done before next stage overwrites sK
    }

    // denominator: per-lane partials cover kv rows of this quad -> reduce
    float rinv[2];
#pragma unroll
    for (int mt = 0; mt < 2; mt++) {
        float v = dsum[mt];
        v += __shfl_xor(v, 16);
        v += __shfl_xor(v, 32);
        rinv[mt] = 1.0f / (v + 1e-6f);
    }

    // normalize + store fp32 to outh32[B,N,H*d], float4 per (dt,mt)
    const int base_row = qt * 128 + wv * 32;
#pragma unroll
    for (int dt = 0; dt < 4; dt++) {
#pragma unroll
        for (int mt = 0; mt < 2; mt++) {
            float4 o4;
            o4.x = O[dt][mt][0] * rinv[mt];
            o4.y = O[dt][mt][1] * rinv[mt];
            o4.z = O[dt][mt][2] * rinv[mt];
            o4.w = O[dt][mt][3] * rinv[mt];
            int row = base_row + mt * 16 + l16;                 // token n
            int col = h * ND + dt * 16 + quad * 4;              // channel c
            *(float4*)(outh32 + (size_t)(b * NN + row) * NC + col) = o4;
        }
    }
}

// ---------------- proj GEMM: out = outh32 * Wproj^T + b_proj, 3-term split ----
// Tile 128x64 (grid 64x12 = 768 blocks for full-CU coverage); wave tile 64x32.
__global__ __launch_bounds__(256) void gemm_proj(
    const float* __restrict__ A,
    const _Float16* __restrict__ Bh, const _Float16* __restrict__ Bl,
    const float* __restrict__ bias, float* __restrict__ out)
{
    __shared__ __align__(16) _Float16 sAh[128 * 32];
    __shared__ __align__(16) _Float16 sAl[128 * 32];
    __shared__ __align__(16) _Float16 sBh[64 * 32];
    __shared__ __align__(16) _Float16 sBl[64 * 32];
    const int tid = threadIdx.x;
    const int lane = tid & 63, wv = tid >> 6;
    const int quad = lane >> 4, l16 = lane & 15;
    const int wm = (wv >> 1) * 64, wn = (wv & 1) * 32;
    const int m0 = blockIdx.x * 128, n0 = blockIdx.y * 64;

    f32x4 acc[4][2] = {};

    for (int k0 = 0; k0 < NC; k0 += 32) {
#pragma unroll
        for (int i = 0; i < 2; i++) {
            int c = tid + i * 256;
            int r = c >> 2, kc = c & 3;
            const float4* pa = (const float4*)(A + (size_t)(m0 + r) * NC + k0 + kc * 8);
            float4 v0 = pa[0], v1 = pa[1];
            f16x8 hi8, lo8;
            hi8[0] = (_Float16)v0.x; lo8[0] = (_Float16)(v0.x - (float)hi8[0]);
            hi8[1] = (_Float16)v0.y; lo8[1] = (_Float16)(v0.y - (float)hi8[1]);
            hi8[2] = (_Float16)v0.z; lo8[2] = (_Float16)(v0.z - (float)hi8[2]);
            hi8[3] = (_Float16)v0.w; lo8[3] = (_Float16)(v0.w - (float)hi8[3]);
            hi8[4] = (_Float16)v1.x; lo8[4] = (_Float16)(v1.x - (float)hi8[4]);
            hi8[5] = (_Float16)v1.y; lo8[5] = (_Float16)(v1.y - (float)hi8[5]);
            hi8[6] = (_Float16)v1.z; lo8[6] = (_Float16)(v1.z - (float)hi8[6]);
            hi8[7] = (_Float16)v1.w; lo8[7] = (_Float16)(v1.w - (float)hi8[7]);
            *(f16x8*)(sAh + c * 8) = hi8;
            *(f16x8*)(sAl + c * 8) = lo8;
        }
        {
            int r = tid >> 2, kc = tid & 3;   // 64 rows x 4 chunks = 256
            size_t goB = (size_t)(n0 + r) * NC + k0 + kc * 8;
            async16(Bh + goB, sBh + tid * 8);
            async16(Bl + goB, sBl + tid * 8);
        }
        __syncthreads();
        f16x8 ah[4], al[4], bh[2], bl[2];
#pragma unroll
        for (int t = 0; t < 4; t++) {
            ah[t] = *(const f16x8*)(sAh + (wm + t * 16 + l16) * 32 + quad * 8);
            al[t] = *(const f16x8*)(sAl + (wm + t * 16 + l16) * 32 + quad * 8);
        }
#pragma unroll
        for (int t = 0; t < 2; t++) {
            bh[t] = *(const f16x8*)(sBh + (wn + t * 16 + l16) * 32 + quad * 8);
            bl[t] = *(const f16x8*)(sBl + (wn + t * 16 + l16) * 32 + quad * 8);
        }
#pragma unroll
        for (int i = 0; i < 4; i++)
#pragma unroll
            for (int j = 0; j < 2; j++)
                acc[i][j] = __builtin_amdgcn_mfma_f32_16x16x32_f16(ah[i], bh[j], acc[i][j], 0, 0, 0);
#pragma unroll
        for (int i = 0; i < 4; i++)
#pragma unroll
            for (int j = 0; j < 2; j++)
                acc[i][j] = __builtin_amdgcn_mfma_f32_16x16x32_f16(al[i], bh[j], acc[i][j], 0, 0, 0);
#pragma unroll
        for (int i = 0; i < 4; i++)
#pragma unroll
            for (int j = 0; j < 2; j++)
                acc[i][j] = __builtin_amdgcn_mfma_f32_16x16x32_f16(ah[i], bl[j], acc[i][j], 0, 0, 0);
        __syncthreads();
    }

#pragma unroll
    for (int i = 0; i < 4; i++) {
#pragma unroll
        for (int j = 0; j < 2; j++) {
#pragma unroll
            for (int r = 0; r < 4; r++) {
                int row = m0 + wm + i * 16 + quad * 4 + r;
                int col = n0 + wn + j * 16 + l16;
                out[(size_t)row * NC + col] = acc[i][j][r] + bias[col];
            }
        }
    }
}

// ---------------- launch ----------------
extern "C" void kernel_launch(void* const* d_in, const int* in_sizes, int n_in,
                              void* d_out, int out_size, void* d_ws, size_t ws_size,
                              hipStream_t stream) {
    const float* x      = (const float*)d_in[0];
    const float* w_qkv  = (const float*)d_in[1];
    const float* w_proj = (const float*)d_in[2];
    const float* b_proj = (const float*)d_in[3];
    const float* alpha  = (const float*)d_in[4];
    const float* beta   = (const float*)d_in[5];
    const float* gamma  = (const float*)d_in[6];
    float* out = (float*)d_out;

    char* ws = (char*)d_ws;
    _Float16* xh     = (_Float16*)(ws + 0);            // dead after gemm_qkv
    _Float16* xl     = (_Float16*)(ws + 12582912);     // dead after gemm_qkv
    float*    outh32 = (float*)(ws + 0);               // overlays xh/xl
    _Float16* wqkvh  = (_Float16*)(ws + 25165824);
    _Float16* wqkvl  = (_Float16*)(ws + 28704768);
    _Float16* wprojh = (_Float16*)(ws + 32243712);
    _Float16* wprojl = (_Float16*)(ws + 33423360);
    _Float16* qh     = (_Float16*)(ws + 34603008);
    _Float16* ql     = (_Float16*)(ws + 47185920);
    _Float16* kh     = (_Float16*)(ws + 59768832);
    _Float16* kl     = (_Float16*)(ws + 72351744);
    _Float16* vt16   = (_Float16*)(ws + 84934656);     // ends 97,517,568 B

    cvt_split_f32<<<6144, 256, 0, stream>>>(x, xh, xl, 1572864);
    cvt_split_f32<<<1728, 256, 0, stream>>>(w_qkv, wqkvh, wqkvl, 442368);
    cvt_split_f32<<<576, 256, 0, stream>>>(w_proj, wprojh, wprojl, 147456);

    gemm_qkv<<<dim3(64, 18), 256, 0, stream>>>(xh, xl, wqkvh, wqkvl, qh, ql, kh, kl, vt16);
    attn_kernel<<<dim3(8, 96), 256, 0, stream>>>(qh, ql, kh, kl, vt16, outh32, alpha, beta, gamma);
    gemm_proj<<<dim3(64, 12), 256, 0, stream>>>(outh32, wprojh, wprojl, b_proj, out);
}

// Round 8
// 215.581 us; speedup vs baseline: 1.6163x; 1.6163x over previous
//
#include <hip/hip_runtime.h>

// L2Q attention, fp16-MFMA. B=8, N=1024, C=768, H=12, d=64, 3C=2304, M=8192.
// R8: hi/lo split ONLY in proj GEMM (the error-critical path; quadratic attn
//     averages q/k quantization noise down by ~sqrt(N)/W). qkv GEMM and attn
//     QK are single-term fp16. attn = R6 structure (K,V staged in LDS,
//     fragment-major = 0 bank conflicts; S^T=K*Q^T register re-pack for PV).

typedef _Float16 f16x8 __attribute__((ext_vector_type(8)));
typedef _Float16 f16x4 __attribute__((ext_vector_type(4)));
typedef float f32x4 __attribute__((ext_vector_type(4)));

#define NB 8
#define NN 1024
#define NC 768
#define NH 12
#define ND 64
#define TC 2304
#define NM 8192

__device__ __forceinline__ void async16(const void* g, void* l) {
    __builtin_amdgcn_global_load_lds(
        (const __attribute__((address_space(1))) void*)g,
        (__attribute__((address_space(3))) void*)l, 16, 0, 0);
}

// ---------------- fp32 -> fp16 convert ----------------
__global__ void cvt_f32_f16(const float* __restrict__ s, _Float16* __restrict__ d, int n4) {
    int i = blockIdx.x * 256 + threadIdx.x;
    if (i < n4) {
        float4 v = ((const float4*)s)[i];
        f16x4 o;
        o[0] = (_Float16)v.x; o[1] = (_Float16)v.y;
        o[2] = (_Float16)v.z; o[3] = (_Float16)v.w;
        ((f16x4*)d)[i] = o;
    }
}

// ---------------- fp32 -> fp16 hi/lo split (proj weights only) ----------------
__global__ void cvt_split_f32(const float* __restrict__ s, _Float16* __restrict__ hi,
                              _Float16* __restrict__ lo, int n4) {
    int i = blockIdx.x * 256 + threadIdx.x;
    if (i < n4) {
        float4 v = ((const float4*)s)[i];
        f16x4 h, l;
        h[0] = (_Float16)v.x; l[0] = (_Float16)(v.x - (float)h[0]);
        h[1] = (_Float16)v.y; l[1] = (_Float16)(v.y - (float)h[1]);
        h[2] = (_Float16)v.z; l[2] = (_Float16)(v.z - (float)h[2]);
        h[3] = (_Float16)v.w; l[3] = (_Float16)(v.w - (float)h[3]);
        ((f16x4*)hi)[i] = h;
        ((f16x4*)lo)[i] = l;
    }
}

// ---------------- qkv GEMM: C[8192,2304] = X16 * Wqkv16^T (1-term) ----------------
// grid (64, 18), 256 threads, 2x2 waves, 64x64 per wave, BK=32.
__global__ __launch_bounds__(256) void gemm_qkv(
    const _Float16* __restrict__ Ah, const _Float16* __restrict__ Bh,
    _Float16* __restrict__ q16, _Float16* __restrict__ k16,
    _Float16* __restrict__ vt16)
{
    __shared__ __align__(16) _Float16 sAh[128 * 32];
    __shared__ __align__(16) _Float16 sBh[128 * 32];
    const int tid = threadIdx.x;
    const int lane = tid & 63, wv = tid >> 6;
    const int quad = lane >> 4, l16 = lane & 15;
    const int wm = (wv >> 1) * 64, wn = (wv & 1) * 64;
    const int m0 = blockIdx.x * 128, n0 = blockIdx.y * 128;

    f32x4 acc[4][4] = {};

    for (int k0 = 0; k0 < NC; k0 += 32) {
#pragma unroll
        for (int i = 0; i < 2; i++) {
            int c = tid + i * 256;
            int r = c >> 2, kc = c & 3;
            async16(Ah + (size_t)(m0 + r) * NC + k0 + kc * 8, sAh + c * 8);
            async16(Bh + (size_t)(n0 + r) * NC + k0 + kc * 8, sBh + c * 8);
        }
        __syncthreads();
        f16x8 ah[4], bh[4];
#pragma unroll
        for (int t = 0; t < 4; t++) {
            ah[t] = *(const f16x8*)(sAh + (wm + t * 16 + l16) * 32 + quad * 8);
            bh[t] = *(const f16x8*)(sBh + (wn + t * 16 + l16) * 32 + quad * 8);
        }
#pragma unroll
        for (int i = 0; i < 4; i++)
#pragma unroll
            for (int j = 0; j < 4; j++)
                acc[i][j] = __builtin_amdgcn_mfma_f32_16x16x32_f16(ah[i], bh[j], acc[i][j], 0, 0, 0);
        __syncthreads();
    }

    // epilogue: q[B,H,N,d], k[B,H,N,d] scalar; v^T[B,H,d,N] vectorized (r-contig)
    const int col = n0 + wn + l16;  // + j*16
#pragma unroll
    for (int j = 0; j < 4; j++) {
        int cj = col + j * 16;
        int which = cj / NC;
        int w2 = cj - which * NC;
        int h = w2 >> 6, dd = w2 & 63;
#pragma unroll
        for (int i = 0; i < 4; i++) {
            int row = m0 + wm + i * 16 + quad * 4;   // + r
            int b = row >> 10, nr = row & 1023;
            int bhd = b * NH + h;
            if (which == 2) {
                f16x4 v4;
                v4[0] = (_Float16)acc[i][j][0];
                v4[1] = (_Float16)acc[i][j][1];
                v4[2] = (_Float16)acc[i][j][2];
                v4[3] = (_Float16)acc[i][j][3];
                *(f16x4*)(vt16 + ((size_t)(bhd * ND + dd)) * NN + nr) = v4;
            } else {
                _Float16* dst = (which == 0 ? q16 : k16);
#pragma unroll
                for (int r = 0; r < 4; r++)
                    dst[((size_t)(bhd * NN + nr + r)) * ND + dd] = (_Float16)acc[i][j][r];
            }
        }
    }
}

// ---------------- fused quadratic-ReLU attention (1-term QK) ----------------
// grid (8 q-tiles, 96 bh), 256 threads = 4 waves; wave handles 32 q-rows.
// S^T = K*Q^T; K-row assignment per fragment (ks2,T): lane i covers kv row
// ks2*32 + 8*(i>>2) + 4T + (i&3), so S^T acc (quad,l16,reg r) IS element
// (4T|r) of the PV B-fragment on the same lane (register re-pack, no LDS
// transpose). K and V^T staged in LDS fragment-major (0 bank conflicts).
__global__ __launch_bounds__(256) void attn_kernel(
    const _Float16* __restrict__ q16, const _Float16* __restrict__ k16,
    const _Float16* __restrict__ vt16, float* __restrict__ outh32,
    const float* __restrict__ alpha, const float* __restrict__ beta,
    const float* __restrict__ gamma)
{
    const int qt = blockIdx.x, bh = blockIdx.y;
    const int b = bh / NH, h = bh - b * NH;
    const int tid = threadIdx.x, lane = tid & 63, wv = tid >> 6;
    const int quad = lane >> 4, l16 = lane & 15;
    const float a2 = alpha[h] * 0.015625f;   // alpha * SCALE^2
    const float b1 = beta[h] * 0.125f;       // beta * SCALE
    const float g0 = gamma[h];

    __shared__ __align__(16) _Float16 sKh[128 * 64];  // 16 KB, fragment-major
    __shared__ __align__(16) _Float16 sVt[64 * 128];  // 16 KB, fragment-major

    const _Float16* Qb = q16 + ((size_t)(bh * NN + qt * 128)) * ND;
    const _Float16* Kb = k16 + (size_t)bh * NN * ND;
    const _Float16* Vb = vt16 + (size_t)bh * ND * NN;

    // Q fragments: 2 m-tiles x 2 d-chunks (MFMA B-operand)
    f16x8 qf[2][2];
#pragma unroll
    for (int mt = 0; mt < 2; mt++)
#pragma unroll
        for (int ksd = 0; ksd < 2; ksd++)
            qf[mt][ksd] = *(const f16x8*)(Qb + (size_t)(wv * 32 + mt * 16 + l16) * ND
                                          + ksd * 32 + quad * 8);

    f32x4 O[4][2] = {};        // [dt][mt]
    float dsum[2] = {0.f, 0.f};

    for (int kt = 0; kt < 8; kt++) {
        // ---- stage K, fragment-major: frag f=(ks2,T,ksd), chunk
        // P = f*64 + q*16 + (a*4+b) holds K[row=ks2*32+8a+4T+b][k=(ksd*4+q)*8..]
#pragma unroll
        for (int i = 0; i < 4; i++) {
            int P = tid + i * 256;
            int f = P >> 6, q = (P >> 4) & 3, a = (P >> 2) & 3, bb = P & 3;
            int ks2 = f >> 2, T = (f >> 1) & 1, ksd = f & 1;
            int row = ks2 * 32 + 8 * a + 4 * T + bb;
            async16(Kb + (size_t)(kt * 128 + row) * ND + (ksd * 4 + q) * 8, sKh + P * 8);
        }
        // ---- stage V^T, fragment-major: frag f=(ks2,dt), chunk
        // P = f*64 + q*16 + l holds V^T[d=dt*16+l][kv=kt*128+(ks2*4+q)*8..]
#pragma unroll
        for (int i = 0; i < 4; i++) {
            int P = tid + i * 256;
            int f = P >> 6, q = (P >> 4) & 3, l = P & 15;
            int ks2 = f >> 2, dt = f & 3;
            async16(Vb + (size_t)(dt * 16 + l) * NN + kt * 128 + (ks2 * 4 + q) * 8,
                    sVt + P * 8);
        }
        __syncthreads();

        // ---- QK^T: 8 concurrent S chains (mt x ks2), T-major phases ----
        f16x8 bfrag[2][4];
#pragma unroll
        for (int T = 0; T < 2; T++) {
            f32x4 S[2][4] = {};
#pragma unroll
            for (int ks2 = 0; ks2 < 4; ks2++) {
#pragma unroll
                for (int ksd = 0; ksd < 2; ksd++) {
                    int addr = (((ks2 * 4 + T * 2 + ksd) * 64) + quad * 16 + l16) * 8;
                    f16x8 ah = *(const f16x8*)(sKh + addr);
#pragma unroll
                    for (int mt = 0; mt < 2; mt++)
                        S[mt][ks2] = __builtin_amdgcn_mfma_f32_16x16x32_f16(ah, qf[mt][ksd], S[mt][ks2], 0, 0, 0);
                }
            }
            // poly + fp16 round; consistent denominator; pack PV B-fragments
#pragma unroll
            for (int mt = 0; mt < 2; mt++) {
#pragma unroll
                for (int ks2 = 0; ks2 < 4; ks2++) {
#pragma unroll
                    for (int r = 0; r < 4; r++) {
                        float s = S[mt][ks2][r];
                        float w = fmaxf(fmaf(fmaf(a2, s, b1), s, g0), 0.f);
                        _Float16 wh = (_Float16)w;
                        dsum[mt] += (float)wh;
                        bfrag[mt][ks2][(T << 2) | r] = wh;
                    }
                }
            }
        }

        // ---- O += V^T x P^T (A = V^T frag from LDS, B = bfrag registers) ----
#pragma unroll
        for (int ks2 = 0; ks2 < 4; ks2++) {
#pragma unroll
            for (int dt = 0; dt < 4; dt++) {
                int addr = (((ks2 * 4 + dt) * 64) + quad * 16 + l16) * 8;
                f16x8 vf = *(const f16x8*)(sVt + addr);
#pragma unroll
                for (int mt = 0; mt < 2; mt++)
                    O[dt][mt] = __builtin_amdgcn_mfma_f32_16x16x32_f16(vf, bfrag[mt][ks2], O[dt][mt], 0, 0, 0);
            }
        }
        __syncthreads();   // compute done before next stage overwrites
    }

    // denominator: per-lane partials cover this quad's kv rows -> reduce
    float rinv[2];
#pragma unroll
    for (int mt = 0; mt < 2; mt++) {
        float v = dsum[mt];
        v += __shfl_xor(v, 16);
        v += __shfl_xor(v, 32);
        rinv[mt] = 1.0f / (v + 1e-6f);
    }

    // normalize + store fp32 to outh32[B,N,H*d], float4 per (dt,mt)
    const int base_row = qt * 128 + wv * 32;
#pragma unroll
    for (int dt = 0; dt < 4; dt++) {
#pragma unroll
        for (int mt = 0; mt < 2; mt++) {
            float4 o4;
            o4.x = O[dt][mt][0] * rinv[mt];
            o4.y = O[dt][mt][1] * rinv[mt];
            o4.z = O[dt][mt][2] * rinv[mt];
            o4.w = O[dt][mt][3] * rinv[mt];
            int row = base_row + mt * 16 + l16;                 // token n
            int col = h * ND + dt * 16 + quad * 4;              // channel c
            *(float4*)(outh32 + (size_t)(b * NN + row) * NC + col) = o4;
        }
    }
}

// ---------------- proj GEMM: out = outh32 * Wproj^T + b_proj, 3-term split ----
// Tile 128x64 (grid 64x12 = 768 blocks); wave tile 64x32.
__global__ __launch_bounds__(256) void gemm_proj(
    const float* __restrict__ A,
    const _Float16* __restrict__ Bh, const _Float16* __restrict__ Bl,
    const float* __restrict__ bias, float* __restrict__ out)
{
    __shared__ __align__(16) _Float16 sAh[128 * 32];
    __shared__ __align__(16) _Float16 sAl[128 * 32];
    __shared__ __align__(16) _Float16 sBh[64 * 32];
    __shared__ __align__(16) _Float16 sBl[64 * 32];
    const int tid = threadIdx.x;
    const int lane = tid & 63, wv = tid >> 6;
    const int quad = lane >> 4, l16 = lane & 15;
    const int wm = (wv >> 1) * 64, wn = (wv & 1) * 32;
    const int m0 = blockIdx.x * 128, n0 = blockIdx.y * 64;

    f32x4 acc[4][2] = {};

    for (int k0 = 0; k0 < NC; k0 += 32) {
#pragma unroll
        for (int i = 0; i < 2; i++) {
            int c = tid + i * 256;
            int r = c >> 2, kc = c & 3;
            const float4* pa = (const float4*)(A + (size_t)(m0 + r) * NC + k0 + kc * 8);
            float4 v0 = pa[0], v1 = pa[1];
            f16x8 hi8, lo8;
            hi8[0] = (_Float16)v0.x; lo8[0] = (_Float16)(v0.x - (float)hi8[0]);
            hi8[1] = (_Float16)v0.y; lo8[1] = (_Float16)(v0.y - (float)hi8[1]);
            hi8[2] = (_Float16)v0.z; lo8[2] = (_Float16)(v0.z - (float)hi8[2]);
            hi8[3] = (_Float16)v0.w; lo8[3] = (_Float16)(v0.w - (float)hi8[3]);
            hi8[4] = (_Float16)v1.x; lo8[4] = (_Float16)(v1.x - (float)hi8[4]);
            hi8[5] = (_Float16)v1.y; lo8[5] = (_Float16)(v1.y - (float)hi8[5]);
            hi8[6] = (_Float16)v1.z; lo8[6] = (_Float16)(v1.z - (float)hi8[6]);
            hi8[7] = (_Float16)v1.w; lo8[7] = (_Float16)(v1.w - (float)hi8[7]);
            *(f16x8*)(sAh + c * 8) = hi8;
            *(f16x8*)(sAl + c * 8) = lo8;
        }
        {
            int r = tid >> 2, kc = tid & 3;   // 64 rows x 4 chunks
            size_t goB = (size_t)(n0 + r) * NC + k0 + kc * 8;
            async16(Bh + goB, sBh + tid * 8);
            async16(Bl + goB, sBl + tid * 8);
        }
        __syncthreads();
        f16x8 ah[4], al[4], bh[2], bl[2];
#pragma unroll
        for (int t = 0; t < 4; t++) {
            ah[t] = *(const f16x8*)(sAh + (wm + t * 16 + l16) * 32 + quad * 8);
            al[t] = *(const f16x8*)(sAl + (wm + t * 16 + l16) * 32 + quad * 8);
        }
#pragma unroll
        for (int t = 0; t < 2; t++) {
            bh[t] = *(const f16x8*)(sBh + (wn + t * 16 + l16) * 32 + quad * 8);
            bl[t] = *(const f16x8*)(sBl + (wn + t * 16 + l16) * 32 + quad * 8);
        }
#pragma unroll
        for (int i = 0; i < 4; i++)
#pragma unroll
            for (int j = 0; j < 2; j++)
                acc[i][j] = __builtin_amdgcn_mfma_f32_16x16x32_f16(ah[i], bh[j], acc[i][j], 0, 0, 0);
#pragma unroll
        for (int i = 0; i < 4; i++)
#pragma unroll
            for (int j = 0; j < 2; j++)
                acc[i][j] = __builtin_amdgcn_mfma_f32_16x16x32_f16(al[i], bh[j], acc[i][j], 0, 0, 0);
#pragma unroll
        for (int i = 0; i < 4; i++)
#pragma unroll
            for (int j = 0; j < 2; j++)
                acc[i][j] = __builtin_amdgcn_mfma_f32_16x16x32_f16(ah[i], bl[j], acc[i][j], 0, 0, 0);
        __syncthreads();
    }

#pragma unroll
    for (int i = 0; i < 4; i++) {
#pragma unroll
        for (int j = 0; j < 2; j++) {
#pragma unroll
            for (int r = 0; r < 4; r++) {
                int row = m0 + wm + i * 16 + quad * 4 + r;
                int col = n0 + wn + j * 16 + l16;
                out[(size_t)row * NC + col] = acc[i][j][r] + bias[col];
            }
        }
    }
}

// ---------------- launch ----------------
extern "C" void kernel_launch(void* const* d_in, const int* in_sizes, int n_in,
                              void* d_out, int out_size, void* d_ws, size_t ws_size,
                              hipStream_t stream) {
    const float* x      = (const float*)d_in[0];
    const float* w_qkv  = (const float*)d_in[1];
    const float* w_proj = (const float*)d_in[2];
    const float* b_proj = (const float*)d_in[3];
    const float* alpha  = (const float*)d_in[4];
    const float* beta   = (const float*)d_in[5];
    const float* gamma  = (const float*)d_in[6];
    float* out = (float*)d_out;

    char* ws = (char*)d_ws;
    float*    outh32 = (float*)(ws + 0);               // 25,165,824 B
    _Float16* xh     = (_Float16*)(ws + 25165824);     // 12,582,912 B
    _Float16* wqkvh  = (_Float16*)(ws + 37748736);     //  3,538,944 B
    _Float16* wprojh = (_Float16*)(ws + 41287680);     //  1,179,648 B
    _Float16* wprojl = (_Float16*)(ws + 42467328);     //  1,179,648 B
    _Float16* q16    = (_Float16*)(ws + 43646976);     // 12,582,912 B
    _Float16* k16    = (_Float16*)(ws + 56229888);     // 12,582,912 B
    _Float16* vt16   = (_Float16*)(ws + 68812800);     // ends 81,395,712 B

    cvt_f32_f16<<<6144, 256, 0, stream>>>(x, xh, 1572864);
    cvt_f32_f16<<<1728, 256, 0, stream>>>(w_qkv, wqkvh, 442368);
    cvt_split_f32<<<576, 256, 0, stream>>>(w_proj, wprojh, wprojl, 147456);

    gemm_qkv<<<dim3(64, 18), 256, 0, stream>>>(xh, wqkvh, q16, k16, vt16);
    attn_kernel<<<dim3(8, 96), 256, 0, stream>>>(q16, k16, vt16, outh32, alpha, beta, gamma);
    gemm_proj<<<dim3(64, 12), 256, 0, stream>>>(outh32, wprojh, wprojl, b_proj, out);
}